// Round 10
// baseline (2785.449 us; speedup 1.0000x reference)
//
#include <hip/hip_runtime.h>
#include <hip/hip_fp16.h>

#define HID   1024
#define NBAT  64
#define NBLK  256
#define NTHR  256
#define AROW  2056              // 2048 + 8 pad (f16 elems)
#define AVEC  257               // AROW/8
#define PLANE 65536             // f16 per activation plane: [256 blk][64 n][4 j]

typedef _Float16 f16;
typedef unsigned long long u64;
typedef __attribute__((ext_vector_type(8))) _Float16 f16x8;
typedef __attribute__((ext_vector_type(4))) float f32x4;

// LDS layout (bytes) — identical to the proven 2119us kernel
#define A_BYTES   (2 * 16 * AROW * 2)    // 131584
#define SCR_OFF   A_BYTES                // f32 [4 wave][16 rows][64 n] = 16384
#define C_OFF     (SCR_OFF + 16384)      // f32 [2][4][64] = 2048
#define BIAS_OFF  (C_OFF + 2048)         // f32 [2][16] = 128
#define HS_OFF    (BIAS_OFF + 128)       // f16 [64][4] = 512
#define LDS_BYTES (HS_OFF + 512)         // 150656 < 160 KiB

// barrier ints (256B-spaced): leaf i: bar[64*i] i<16 | root: bar[64*16] |
// release flag i: bar[64*(17+i)] i<16 | xcd elect x: bar[64*(33+x)] x<8
#define BAR_INTS  (64 * 41)

__device__ __forceinline__ float sigm(float x) { return 1.f / (1.f + __expf(-x)); }
__device__ __forceinline__ float tanh_f(float x) {
  float xc = fminf(fmaxf(x, -10.f), 10.f);
  float e = __expf(2.f * xc);
  return (e - 1.f) / (e + 1.f);
}

// sc1 write-through store (coherent via MALL, no cache-maintenance ops)
__device__ __forceinline__ void st64c(void* p, u64 v) {
  __hip_atomic_store((u64*)p, v, __ATOMIC_RELAXED, __HIP_MEMORY_SCOPE_AGENT);
}

__global__ void bar_init(int* bar) {
  int i = threadIdx.x;
  #pragma unroll
  for (int k = 0; k < 3; ++k) {
    int idx = i + k * 1024;
    if (idx < BAR_INTS) bar[idx] = 0;
  }
}

// R7 structure (proven 2119us) + barrier-overlapped stale GEMM:
// Block b owns units [4b,4b+4) both layers; weights f16 in LDS.
// Per phase, waves 0-1 do the W_ih (fresh-vector) GEMM at phase top;
// waves 2-3 computed the W_hh (2-phase-old vector) GEMM for THIS phase
// during the PREVIOUS phase's barrier window (overlapped with tid0's poll),
// reading the then-fresh plane straight from XCD-L2.
// Coherence: h/x/out sc1 write-through; B plain cached loads; ONE leader
// buffer_inv per XCD per phase at phase top (post-release). Every address's
// pre-write cached copies see >=2 invs before its next fresh read.
__global__ __launch_bounds__(NTHR, 1) void lstm_kernel(
    const float* __restrict__ x0, const float* __restrict__ h0,
    const float* __restrict__ c0, const float* __restrict__ Wih,
    const float* __restrict__ Whh, const float* __restrict__ bih,
    const float* __restrict__ bhh, const int* __restrict__ lenp,
    float* __restrict__ out, int* __restrict__ bar, f16* __restrict__ planes)
{
  extern __shared__ char smem[];
  f16*   Alds  = (f16*)smem;
  float* scr   = (float*)(smem + SCR_OFF);
  float* cS    = (float*)(smem + C_OFF);
  float* biasS = (float*)(smem + BIAS_OFF);
  f16*   hS    = (f16*)(smem + HS_OFF);

  const int tid  = threadIdx.x;
  const int blk  = blockIdx.x;
  const int wave = tid >> 6;
  const int lane = tid & 63;
  const int quad = lane >> 4;
  const int l15  = lane & 15;
  const int T    = *lenp;

  f16* l0P[2] = { planes,             planes + PLANE };
  f16* l1P[2] = { planes + 2 * PLANE, planes + 3 * PLANE };
  f16* xP     =   planes + 4 * PLANE;

  const int leafid = blk & 15;
  int* leaf  = bar + 64 * leafid;
  int* rootc = bar + 64 * 16;
  int* relme = bar + 64 * (17 + leafid);

  // ---- physical XCD id + one-time leader election ----
  unsigned xcc;
  asm volatile("s_getreg_b32 %0, hwreg(HW_REG_XCC_ID)" : "=s"(xcc));
  xcc &= 7;
  int is_leader = 0;
  if (tid == 0) {
    int p = __hip_atomic_fetch_add(bar + 64 * (33 + xcc), 1, __ATOMIC_RELAXED,
                                   __HIP_MEMORY_SCOPE_AGENT);
    is_leader = (p == 0);
  }

  // ---- stage weights (f32 -> f16) into LDS ----
  {
    int r    = tid >> 2;
    int part = tid & 3;
    int l    = r >> 5;
    int m    = (r >> 1) & 15;
    int half = r & 1;
    int g    = m >> 2, j = m & 3;
    size_t grow = (size_t)g * HID + blk * 4 + j;
    const float* srcW = (half ? Whh : Wih) + ((size_t)l * 4 * HID + grow) * HID + part * 256;
    f16x8* dst = (f16x8*)(Alds + (size_t)(l * 16 + m) * AROW + half * HID + part * 256);
    const float4* s4 = (const float4*)srcW;
    #pragma unroll 4
    for (int i = 0; i < 32; ++i) {
      float4 w0 = s4[2 * i], w1 = s4[2 * i + 1];
      f16x8 o = {(f16)w0.x, (f16)w0.y, (f16)w0.z, (f16)w0.w,
                 (f16)w1.x, (f16)w1.y, (f16)w1.z, (f16)w1.w};
      dst[i] = o;
    }
  }
  // ---- biases ----
  if (tid < 32) {
    int l = tid >> 4, m = tid & 15;
    int g = m >> 2, j = m & 3;
    size_t row = (size_t)g * HID + blk * 4 + j;
    biasS[l * 16 + m] = bih[(size_t)l * 4 * HID + row] + bhh[(size_t)l * 4 * HID + row];
  }
  // ---- c state (LDS) ----
  {
    int j = tid >> 6, n = tid & 63;
    #pragma unroll
    for (int l = 0; l < 2; ++l)
      cS[l * 256 + j * 64 + n] =
          c0[(size_t)l * NBAT * HID + (size_t)n * HID + blk * 4 + j];
  }
  // ---- h0 -> parity-1 planes (block-contiguous, 8B/lane) ----
  if (tid < 128) {
    int l = tid >> 6, n = tid & 63;
    const float* hp = h0 + (size_t)l * NBAT * HID + (size_t)n * HID + blk * 4;
    union { u64 q; f16 h[4]; } pk;
    pk.h[0] = (f16)hp[0]; pk.h[1] = (f16)hp[1]; pk.h[2] = (f16)hp[2]; pk.h[3] = (f16)hp[3];
    st64c((l == 0 ? l0P[1] : l1P[1]) + blk * 256 + n * 4, pk.q);
  }
  // ---- x0 -> xP ----
  if (tid < 64) {
    int n = tid;
    const float* xp = x0 + (size_t)n * HID + blk * 4;
    union { u64 q; f16 h[4]; } pk;
    pk.h[0] = (f16)xp[0]; pk.h[1] = (f16)xp[1]; pk.h[2] = (f16)xp[2]; pk.h[3] = (f16)xp[3];
    st64c(xP + blk * 256 + n * 4, pk.q);
  }
  // one-time safety inv (poison/stale lines) before first arrival
  if (wave == 0) asm volatile("buffer_inv sc1" ::: "memory");

  int epoch = 1;
  const f16x8* Av = (const f16x8*)Alds;

  // ---- barrier pieces ----
  #define ARRIVE()                                                                \
    do { asm volatile("s_waitcnt vmcnt(0)" ::: "memory"); __syncthreads(); } while (0)

  #define HANDSHAKE()                                                             \
    do {                                                                          \
      int prev = __hip_atomic_fetch_add(leaf, 1, __ATOMIC_RELAXED,                \
                                        __HIP_MEMORY_SCOPE_AGENT);                \
      bool released = false;                                                      \
      if (prev == 16 * epoch - 1) {                                               \
        int rprev = __hip_atomic_fetch_add(rootc, 1, __ATOMIC_RELAXED,            \
                                           __HIP_MEMORY_SCOPE_AGENT);            \
        if (rprev == 16 * epoch - 1) {                                            \
          _Pragma("unroll")                                                       \
          for (int i = 0; i < 16; ++i)                                            \
            __hip_atomic_fetch_add(bar + 64 * (17 + i), 1, __ATOMIC_RELAXED,      \
                                   __HIP_MEMORY_SCOPE_AGENT);                     \
          released = true;                                                        \
        }                                                                         \
      }                                                                           \
      if (!released) {                                                            \
        while (__hip_atomic_fetch_add(relme, 0, __ATOMIC_RELAXED,                 \
                                      __HIP_MEMORY_SCOPE_AGENT) < epoch)          \
          __builtin_amdgcn_s_sleep(1);                                            \
      }                                                                           \
    } while (0)

  #define RELEASE_SYNC() do { epoch++; __syncthreads(); } while (0)

  // ---- parametrized GEMM into this wave's scr quarter (R7-proven mapping) ----
  // Waves 0-1 use it with the fresh plane (W_ih cols); waves 2-3 with the
  // stale plane (W_hh cols). k = wave*512 + quad*8 + 32*kk + j.
  #define GEMM_SCR(LIDX, PSRC)                                                    \
    do {                                                                          \
      const f16* psrc_ = (PSRC);                                                  \
      const int ubq_ = (wave & 1) * 128 + quad * 2;                               \
      const f16* pr0 = psrc_ + ubq_ * 256 + (l15 +  0) * 4;                       \
      const f16* pr1 = psrc_ + ubq_ * 256 + (l15 + 16) * 4;                       \
      const f16* pr2 = psrc_ + ubq_ * 256 + (l15 + 32) * 4;                       \
      const f16* pr3 = psrc_ + ubq_ * 256 + (l15 + 48) * 4;                       \
      int aoff_ = ((LIDX) * 16 + l15) * AVEC + wave * 64 + quad;                  \
      f32x4 a0 = {0.f, 0.f, 0.f, 0.f}, a1 = a0, a2 = a0, a3 = a0;                 \
      _Pragma("unroll")                                                           \
      for (int kk = 0; kk < 16; ++kk) {                                           \
        f16x8 af = Av[aoff_ + kk * 4];                                            \
        union { u64 q[2]; f16x8 v; } b0, b1, b2, b3;                              \
        const f16* k0 = pr0 + kk * 2048;                                          \
        const f16* k1 = pr1 + kk * 2048;                                          \
        const f16* k2 = pr2 + kk * 2048;                                          \
        const f16* k3 = pr3 + kk * 2048;                                          \
        b0.q[0] = *(const u64*)k0; b0.q[1] = *(const u64*)(k0 + 256);             \
        b1.q[0] = *(const u64*)k1; b1.q[1] = *(const u64*)(k1 + 256);             \
        b2.q[0] = *(const u64*)k2; b2.q[1] = *(const u64*)(k2 + 256);             \
        b3.q[0] = *(const u64*)k3; b3.q[1] = *(const u64*)(k3 + 256);             \
        a0 = __builtin_amdgcn_mfma_f32_16x16x32_f16(af, b0.v, a0, 0, 0, 0);       \
        a1 = __builtin_amdgcn_mfma_f32_16x16x32_f16(af, b1.v, a1, 0, 0, 0);       \
        a2 = __builtin_amdgcn_mfma_f32_16x16x32_f16(af, b2.v, a2, 0, 0, 0);       \
        a3 = __builtin_amdgcn_mfma_f32_16x16x32_f16(af, b3.v, a3, 0, 0, 0);       \
      }                                                                           \
      float* sc_ = scr + wave * 1024;                                             \
      _Pragma("unroll")                                                           \
      for (int r = 0; r < 4; ++r) {                                               \
        int base_ = (quad * 4 + r) * 64 + l15;                                    \
        sc_[base_ +  0] = a0[r];                                                  \
        sc_[base_ + 16] = a1[r];                                                  \
        sc_[base_ + 32] = a2[r];                                                  \
        sc_[base_ + 48] = a3[r];                                                  \
      }                                                                           \
    } while (0)

  #define ELEMENTWISE(LIDX)                                                       \
    do {                                                                          \
      int j = tid >> 6, n = tid & 63;                                             \
      float gate[4];                                                              \
      _Pragma("unroll")                                                           \
      for (int g = 0; g < 4; ++g) {                                               \
        int b0i = (g * 4 + j) * 64 + n;                                           \
        gate[g] = scr[b0i] + scr[1024 + b0i] + scr[2048 + b0i] + scr[3072 + b0i]  \
                + biasS[(LIDX) * 16 + g * 4 + j];                                 \
      }                                                                           \
      float cold = cS[(LIDX) * 256 + j * 64 + n];                                 \
      float cn = sigm(gate[1]) * cold + sigm(gate[0]) * tanh_f(gate[2]);          \
      float hn = sigm(gate[3]) * tanh_f(cn);                                      \
      cS[(LIDX) * 256 + j * 64 + n] = cn;                                         \
      hS[n * 4 + j] = (f16)hn;                                                    \
    } while (0)

  #define STORES(LIDX)                                                            \
    do {                                                                          \
      if (tid < 64) {                                                             \
        int n = tid;                                                              \
        union { u64 q; f16 h[4]; } pk;                                            \
        pk.q = *(const u64*)(hS + n * 4);                                         \
        st64c(((LIDX) == 0 ? l0P[wp] : l1P[wp]) + blk * 256 + n * 4, pk.q);       \
        if ((LIDX) == 1) {                                                        \
          union { u64 q; float f[2]; } o0, o1;                                    \
          o0.f[0] = (float)pk.h[0]; o0.f[1] = (float)pk.h[1];                     \
          o1.f[0] = (float)pk.h[2]; o1.f[1] = (float)pk.h[3];                     \
          float* op = out + (size_t)n * T * HID + (size_t)t * HID + blk * 4;      \
          st64c(op, o0.q);                                                        \
          st64c(op + 2, o1.q);                                                    \
        }                                                                         \
      }                                                                           \
    } while (0)

  // ---- initial barrier, then prime phase-0 stale partials (Whh_l0 . h0_l0) ----
  ARRIVE();
  if (tid == 0) HANDSHAKE();
  RELEASE_SYNC();
  if (wave >= 2) GEMM_SCR(0, l0P[1]);

  for (int t = 0; t < T; ++t) {
    const int wp = t & 1, rp = wp ^ 1;

    // ================= layer 0 phase =================
    if (tid == 0 && is_leader) asm volatile("buffer_inv sc1" ::: "memory");
    if (wave < 2) GEMM_SCR(0, (t == 0) ? xP : l1P[rp]);
    __syncthreads();
    ELEMENTWISE(0);
    __syncthreads();
    STORES(0);
    ARRIVE();
    if (tid == 0) HANDSHAKE();
    else if (wave >= 2) GEMM_SCR(1, l1P[rp]);   // stale for layer-1 phase (L2-hit)
    RELEASE_SYNC();

    // ================= layer 1 phase =================
    if (tid == 0 && is_leader) asm volatile("buffer_inv sc1" ::: "memory");
    if (wave < 2) GEMM_SCR(1, l0P[wp]);
    __syncthreads();
    ELEMENTWISE(1);
    __syncthreads();
    STORES(1);
    ARRIVE();
    if (tid == 0) HANDSHAKE();
    else if (wave >= 2) { if (t + 1 < T) GEMM_SCR(0, l0P[wp]); }  // stale for next step's layer 0
    RELEASE_SYNC();
  }
}

extern "C" void kernel_launch(void* const* d_in, const int* in_sizes, int n_in,
                              void* d_out, int out_size, void* d_ws, size_t ws_size,
                              hipStream_t stream) {
  const float* x0  = (const float*)d_in[0];
  const float* h0  = (const float*)d_in[1];
  const float* c0  = (const float*)d_in[2];
  const float* Wih = (const float*)d_in[3];
  const float* Whh = (const float*)d_in[4];
  const float* bih = (const float*)d_in[5];
  const float* bhh = (const float*)d_in[6];
  const int* lenp  = (const int*)d_in[7];
  float* out = (float*)d_out;

  int* bar    = (int*)d_ws;
  f16* planes = (f16*)((char*)d_ws + 16384);   // 5 planes x 128 KB

  hipFuncSetAttribute((const void*)lstm_kernel,
                      hipFuncAttributeMaxDynamicSharedMemorySize, LDS_BYTES);

  bar_init<<<1, 1024, 0, stream>>>(bar);

  void* args[] = {&x0, &h0, &c0, &Wih, &Whh, &bih, &bhh, &lenp, &out, &bar, &planes};
  hipLaunchCooperativeKernel((void*)lstm_kernel, dim3(NBLK), dim3(NTHR),
                             args, LDS_BYTES, stream);
}

// Round 11
// 2408.152 us; speedup vs baseline: 1.1567x; 1.1567x over previous
//
#include <hip/hip_runtime.h>
#include <hip/hip_fp16.h>

#define HID   1024
#define NBAT  64
#define NBLK  256
#define NTHR  256
#define AROW  1032              // 1024 + 8 pad f16 per weight row (2-way bank alias, free)
#define AVEC  129               // AROW/8
#define PLANE 65536             // f16 per activation plane: [256 blk][64 n][4 j]

typedef _Float16 f16;
typedef unsigned long long u64;
typedef __attribute__((ext_vector_type(8))) _Float16 f16x8;
typedef __attribute__((ext_vector_type(4))) float f32x4;

// LDS layout (bytes)
// Weights: 4 halves {ih_l0, hh_l0, ih_l1, hh_l1} x 16 rows x 1032 f16
#define A_BYTES   (4 * 16 * AROW * 2)    // 132096
#define SCR_OFF   A_BYTES                // f32: fresh 2048 + stale 2x2048 = 24576 B
#define C_OFF     (SCR_OFF + 24576)      // f32 [2][4][64] = 2048
#define BIAS_OFF  (C_OFF + 2048)         // f32 [2][16] = 128
#define HS_OFF    (BIAS_OFF + 128)       // f16 [64][4] = 512
#define LDS_BYTES (HS_OFF + 512)         // 159360 < 163840

// barrier ints (256B-spaced): leaf i: bar[64*i] i<16 | root: bar[64*16] |
// release flag i: bar[64*(17+i)] i<16 | xcd elect x: bar[64*(33+x)] x<8
#define BAR_INTS  (64 * 41)

__device__ __forceinline__ float sigm(float x) { return 1.f / (1.f + __expf(-x)); }
__device__ __forceinline__ float tanh_f(float x) {
  float xc = fminf(fmaxf(x, -10.f), 10.f);
  float e = __expf(2.f * xc);
  return (e - 1.f) / (e + 1.f);
}

// sc1 write-through store (coherent via MALL, no cache-maintenance ops)
__device__ __forceinline__ void st64c(void* p, u64 v) {
  __hip_atomic_store((u64*)p, v, __ATOMIC_RELAXED, __HIP_MEMORY_SCOPE_AGENT);
}

__global__ void bar_init(int* bar) {
  int i = threadIdx.x;
  #pragma unroll
  for (int k = 0; k < 3; ++k) {
    int idx = i + k * 1024;
    if (idx < BAR_INTS) bar[idx] = 0;
  }
}

// R7 core (proven 2119us) + single-plane phases:
// At every phase ALL 4 waves read the ONE plane written last phase:
//   l0@t:  w0-1: W_ih_l0 x (x_t==h1_{t-1})  [fresh, this phase]
//          w2-3: W_hh_l1 x h1_{t-1}         [stale, for l1@t]  -- same plane
//   l1@t:  w0-1: W_ih_l1 x h0_t             [fresh]
//          w2-3: W_hh_l0 x h0_t             [stale, for l0@t+1] -- same plane
// Stale partials live in double-buffered LDS scratch across the barrier.
// Halves per-phase L2 broadcast (128KB/CU). Elementwise sum order identical
// to R7 (ih[0:512]+ih[512:1024]+hh[0:512]+hh[512:1024]) => bit-identical out.
// Coherence: sc1 write-through stores; plain cached B loads; leader buffer_inv
// once per STEP (l0-phase tops): any pre-write cached copy of a plane still
// sees >=1 inv before its write (planes of a given parity are re-read only
// every other step), and post-write reads pull valid data from MALL.
__global__ __launch_bounds__(NTHR, 1) void lstm_kernel(
    const float* __restrict__ x0, const float* __restrict__ h0,
    const float* __restrict__ c0, const float* __restrict__ Wih,
    const float* __restrict__ Whh, const float* __restrict__ bih,
    const float* __restrict__ bhh, const int* __restrict__ lenp,
    float* __restrict__ out, int* __restrict__ bar, f16* __restrict__ planes)
{
  extern __shared__ char smem[];
  f16*   Alds  = (f16*)smem;
  float* scr   = (float*)(smem + SCR_OFF);   // [0,2048): fresh; [2048,6144): stale x2
  float* cS    = (float*)(smem + C_OFF);
  float* biasS = (float*)(smem + BIAS_OFF);
  f16*   hS    = (f16*)(smem + HS_OFF);

  const int tid  = threadIdx.x;
  const int blk  = blockIdx.x;
  const int wave = tid >> 6;
  const int lane = tid & 63;
  const int quad = lane >> 4;
  const int l15  = lane & 15;
  const int T    = *lenp;

  // Entry inv: drop harness poison lines (possibly dirty in this XCD's L2)
  // BEFORE any sc1 plane store, so no stale writeback can clobber MALL.
  if (tid == 0) asm volatile("buffer_inv sc1" ::: "memory");

  f16* l0P[2] = { planes,             planes + PLANE };
  f16* l1P[2] = { planes + 2 * PLANE, planes + 3 * PLANE };
  f16* xP     =   planes + 4 * PLANE;

  const int leafid = blk & 15;
  int* leaf  = bar + 64 * leafid;
  int* rootc = bar + 64 * 16;
  int* relme = bar + 64 * (17 + leafid);

  // ---- physical XCD id + one-time leader election ----
  unsigned xcc;
  asm volatile("s_getreg_b32 %0, hwreg(HW_REG_XCC_ID)" : "=s"(xcc));
  xcc &= 7;
  int is_leader = 0;
  if (tid == 0) {
    int p = __hip_atomic_fetch_add(bar + 64 * (33 + xcc), 1, __ATOMIC_RELAXED,
                                   __HIP_MEMORY_SCOPE_AGENT);
    is_leader = (p == 0);
  }

  // ---- stage weights (f32 -> f16) into LDS: 64 rows of 1024, 4 threads/row ----
  // half h: 0=W_ih l0, 1=W_hh l0, 2=W_ih l1, 3=W_hh l1; row m = g*4+j
  {
    int r    = tid >> 2;            // 0..63
    int part = tid & 3;             // 256-elem chunk
    int half = r >> 4;
    int m    = r & 15;
    int l    = half >> 1;
    int g    = m >> 2, j = m & 3;
    size_t grow = (size_t)g * HID + blk * 4 + j;
    const float* srcW = ((half & 1) ? Whh : Wih) + ((size_t)l * 4 * HID + grow) * HID + part * 256;
    f16x8* dst = (f16x8*)(Alds + (size_t)(half * 16 + m) * AROW + part * 256);
    const float4* s4 = (const float4*)srcW;
    #pragma unroll 4
    for (int i = 0; i < 32; ++i) {
      float4 w0 = s4[2 * i], w1 = s4[2 * i + 1];
      f16x8 o = {(f16)w0.x, (f16)w0.y, (f16)w0.z, (f16)w0.w,
                 (f16)w1.x, (f16)w1.y, (f16)w1.z, (f16)w1.w};
      dst[i] = o;
    }
  }
  // ---- biases ----
  if (tid < 32) {
    int l = tid >> 4, m = tid & 15;
    int g = m >> 2, j = m & 3;
    size_t row = (size_t)g * HID + blk * 4 + j;
    biasS[l * 16 + m] = bih[(size_t)l * 4 * HID + row] + bhh[(size_t)l * 4 * HID + row];
  }
  // ---- c state (LDS) ----
  {
    int j = tid >> 6, n = tid & 63;
    #pragma unroll
    for (int l = 0; l < 2; ++l)
      cS[l * 256 + j * 64 + n] =
          c0[(size_t)l * NBAT * HID + (size_t)n * HID + blk * 4 + j];
  }
  // ---- h0 -> parity-1 planes (block-contiguous, 8B/lane, sc1) ----
  if (tid < 128) {
    int l = tid >> 6, n = tid & 63;
    const float* hp = h0 + (size_t)l * NBAT * HID + (size_t)n * HID + blk * 4;
    union { u64 q; f16 h[4]; } pk;
    pk.h[0] = (f16)hp[0]; pk.h[1] = (f16)hp[1]; pk.h[2] = (f16)hp[2]; pk.h[3] = (f16)hp[3];
    st64c((l == 0 ? l0P[1] : l1P[1]) + blk * 256 + n * 4, pk.q);
  }
  // ---- x0 -> xP (sc1) ----
  if (tid < 64) {
    int n = tid;
    const float* xp = x0 + (size_t)n * HID + blk * 4;
    union { u64 q; f16 h[4]; } pk;
    pk.h[0] = (f16)xp[0]; pk.h[1] = (f16)xp[1]; pk.h[2] = (f16)xp[2]; pk.h[3] = (f16)xp[3];
    st64c(xP + blk * 256 + n * 4, pk.q);
  }

  int epoch = 1;
  const f16x8* Av = (const f16x8*)Alds;

  #define ARRIVE()                                                                \
    do { asm volatile("s_waitcnt vmcnt(0)" ::: "memory"); __syncthreads(); } while (0)

  #define HANDSHAKE()                                                             \
    do {                                                                          \
      int prev = __hip_atomic_fetch_add(leaf, 1, __ATOMIC_RELAXED,                \
                                        __HIP_MEMORY_SCOPE_AGENT);                \
      bool released = false;                                                      \
      if (prev == 16 * epoch - 1) {                                               \
        int rprev = __hip_atomic_fetch_add(rootc, 1, __ATOMIC_RELAXED,            \
                                           __HIP_MEMORY_SCOPE_AGENT);            \
        if (rprev == 16 * epoch - 1) {                                            \
          _Pragma("unroll")                                                       \
          for (int i = 0; i < 16; ++i)                                            \
            __hip_atomic_fetch_add(bar + 64 * (17 + i), 1, __ATOMIC_RELAXED,      \
                                   __HIP_MEMORY_SCOPE_AGENT);                     \
          released = true;                                                        \
        }                                                                         \
      }                                                                           \
      if (!released) {                                                            \
        while (__hip_atomic_fetch_add(relme, 0, __ATOMIC_RELAXED,                 \
                                      __HIP_MEMORY_SCOPE_AGENT) < epoch)          \
          __builtin_amdgcn_s_sleep(1);                                            \
      }                                                                           \
    } while (0)

  #define BARRIER()                                                               \
    do { ARRIVE(); if (tid == 0) HANDSHAKE(); epoch++; __syncthreads(); } while (0)

  // ---- one K=512 GEMM into a scratch quarter (R7-proven index mapping) ----
  // k = (wave&1)*512 + quad*8 + 32*kk + j over the plane's 1024-long vector.
  #define GEMM_SCR(HALF, PSRC, SCQ)                                               \
    do {                                                                          \
      const f16* psrc_ = (PSRC);                                                  \
      const int ubq_ = (wave & 1) * 128 + quad * 2;                               \
      const f16* pr0 = psrc_ + ubq_ * 256 + (l15 +  0) * 4;                       \
      const f16* pr1 = psrc_ + ubq_ * 256 + (l15 + 16) * 4;                       \
      const f16* pr2 = psrc_ + ubq_ * 256 + (l15 + 32) * 4;                       \
      const f16* pr3 = psrc_ + ubq_ * 256 + (l15 + 48) * 4;                       \
      int aoff_ = ((HALF) * 16 + l15) * AVEC + (wave & 1) * 64 + quad;            \
      f32x4 a0 = {0.f, 0.f, 0.f, 0.f}, a1 = a0, a2 = a0, a3 = a0;                 \
      _Pragma("unroll")                                                           \
      for (int kk = 0; kk < 16; ++kk) {                                           \
        f16x8 af = Av[aoff_ + kk * 4];                                            \
        union { u64 q[2]; f16x8 v; } b0, b1, b2, b3;                              \
        const f16* k0 = pr0 + kk * 2048;                                          \
        const f16* k1 = pr1 + kk * 2048;                                          \
        const f16* k2 = pr2 + kk * 2048;                                          \
        const f16* k3 = pr3 + kk * 2048;                                          \
        b0.q[0] = *(const u64*)k0; b0.q[1] = *(const u64*)(k0 + 256);             \
        b1.q[0] = *(const u64*)k1; b1.q[1] = *(const u64*)(k1 + 256);             \
        b2.q[0] = *(const u64*)k2; b2.q[1] = *(const u64*)(k2 + 256);             \
        b3.q[0] = *(const u64*)k3; b3.q[1] = *(const u64*)(k3 + 256);             \
        a0 = __builtin_amdgcn_mfma_f32_16x16x32_f16(af, b0.v, a0, 0, 0, 0);       \
        a1 = __builtin_amdgcn_mfma_f32_16x16x32_f16(af, b1.v, a1, 0, 0, 0);       \
        a2 = __builtin_amdgcn_mfma_f32_16x16x32_f16(af, b2.v, a2, 0, 0, 0);       \
        a3 = __builtin_amdgcn_mfma_f32_16x16x32_f16(af, b3.v, a3, 0, 0, 0);       \
      }                                                                           \
      float* sc_ = (SCQ);                                                         \
      _Pragma("unroll")                                                           \
      for (int r = 0; r < 4; ++r) {                                               \
        int base_ = (quad * 4 + r) * 64 + l15;                                    \
        sc_[base_ +  0] = a0[r];                                                  \
        sc_[base_ + 16] = a1[r];                                                  \
        sc_[base_ + 32] = a2[r];                                                  \
        sc_[base_ + 48] = a3[r];                                                  \
      }                                                                           \
    } while (0)

  #define ELEMENTWISE(LIDX, RBUF)                                                 \
    do {                                                                          \
      int j = tid >> 6, n = tid & 63;                                             \
      const float* stale_ = scr + 2048 + (RBUF) * 2048;                           \
      float gate[4];                                                              \
      _Pragma("unroll")                                                           \
      for (int g = 0; g < 4; ++g) {                                               \
        int b0i = (g * 4 + j) * 64 + n;                                           \
        gate[g] = scr[b0i] + scr[1024 + b0i] + stale_[b0i] + stale_[1024 + b0i]   \
                + biasS[(LIDX) * 16 + g * 4 + j];                                 \
      }                                                                           \
      float cold = cS[(LIDX) * 256 + j * 64 + n];                                 \
      float cn = sigm(gate[1]) * cold + sigm(gate[0]) * tanh_f(gate[2]);          \
      float hn = sigm(gate[3]) * tanh_f(cn);                                      \
      cS[(LIDX) * 256 + j * 64 + n] = cn;                                         \
      hS[n * 4 + j] = (f16)hn;                                                    \
    } while (0)

  #define STORES(LIDX)                                                            \
    do {                                                                          \
      if (tid < 64) {                                                             \
        int n = tid;                                                              \
        union { u64 q; f16 h[4]; } pk;                                            \
        pk.q = *(const u64*)(hS + n * 4);                                         \
        st64c(((LIDX) == 0 ? l0P[wp] : l1P[wp]) + blk * 256 + n * 4, pk.q);       \
        if ((LIDX) == 1) {                                                        \
          union { u64 q; float f[2]; } o0, o1;                                    \
          o0.f[0] = (float)pk.h[0]; o0.f[1] = (float)pk.h[1];                     \
          o1.f[0] = (float)pk.h[2]; o1.f[1] = (float)pk.h[3];                     \
          float* op = out + (size_t)n * T * HID + (size_t)t * HID + blk * 4;      \
          st64c(op, o0.q);                                                        \
          st64c(op + 2, o1.q);                                                    \
        }                                                                         \
      }                                                                           \
    } while (0)

  // ---- initial barrier, then prime: stale partials for (t=0, l0) ----
  BARRIER();
  if (wave >= 2) GEMM_SCR(1 /*hh_l0*/, l0P[1], scr + 2048 + (wave - 2) * 1024);

  int sbuf = 0;   // phase reads stale buf sbuf, w2-3 write buf sbuf^1

  for (int t = 0; t < T; ++t) {
    const int wp = t & 1, rp = wp ^ 1;

    // ================= layer 0 phase =================
    if (tid == 0 && is_leader) asm volatile("buffer_inv sc1" ::: "memory");
    if (wave < 2) GEMM_SCR(0 /*ih_l0*/, (t == 0) ? xP : l1P[rp], scr + wave * 1024);
    else          GEMM_SCR(3 /*hh_l1*/, l1P[rp],
                           scr + 2048 + (sbuf ^ 1) * 2048 + (wave - 2) * 1024);
    __syncthreads();
    ELEMENTWISE(0, sbuf);
    __syncthreads();
    STORES(0);
    BARRIER();
    sbuf ^= 1;

    // ================= layer 1 phase (no inv needed) =================
    if (wave < 2) GEMM_SCR(2 /*ih_l1*/, l0P[wp], scr + wave * 1024);
    else          GEMM_SCR(1 /*hh_l0*/, l0P[wp],
                           scr + 2048 + (sbuf ^ 1) * 2048 + (wave - 2) * 1024);
    __syncthreads();
    ELEMENTWISE(1, sbuf);
    __syncthreads();
    STORES(1);
    BARRIER();
    sbuf ^= 1;
  }
}

extern "C" void kernel_launch(void* const* d_in, const int* in_sizes, int n_in,
                              void* d_out, int out_size, void* d_ws, size_t ws_size,
                              hipStream_t stream) {
  const float* x0  = (const float*)d_in[0];
  const float* h0  = (const float*)d_in[1];
  const float* c0  = (const float*)d_in[2];
  const float* Wih = (const float*)d_in[3];
  const float* Whh = (const float*)d_in[4];
  const float* bih = (const float*)d_in[5];
  const float* bhh = (const float*)d_in[6];
  const int* lenp  = (const int*)d_in[7];
  float* out = (float*)d_out;

  int* bar    = (int*)d_ws;
  f16* planes = (f16*)((char*)d_ws + 16384);   // 5 planes x 128 KB

  hipFuncSetAttribute((const void*)lstm_kernel,
                      hipFuncAttributeMaxDynamicSharedMemorySize, LDS_BYTES);

  bar_init<<<1, 1024, 0, stream>>>(bar);

  void* args[] = {&x0, &h0, &c0, &Wih, &Whh, &bih, &bhh, &lenp, &out, &bar, &planes};
  hipLaunchCooperativeKernel((void*)lstm_kernel, dim3(NBLK), dim3(NTHR),
                             args, LDS_BYTES, stream);
}